// Round 1
// baseline (761.893 us; speedup 1.0000x reference)
//
#include <hip/hip_runtime.h>
#include <math.h>

// Problem constants (B=4, T=4096, D=4096, N_POS=16), fp32 in/out.
constexpr int D    = 4096;
constexpr int D4   = D / 4;      // float4 count per row
constexpr int NPOS = 16;
constexpr int RPB  = 4;          // rows per block (amortizes PV cache traffic)
constexpr float SCALE = 0.015625f;  // 1/sqrt(4096)
constexpr float EPS   = 1e-12f;

// Kernel 0: L2-normalize the 16 codebook rows into workspace.
__global__ __launch_bounds__(256) void normalize_pos_kernel(
        const float* __restrict__ pos_emb, float* __restrict__ pos_vecs) {
    const int n   = blockIdx.x;     // one block per codebook row
    const int tid = threadIdx.x;
    const float4* src = reinterpret_cast<const float4*>(pos_emb) + n * D4;
    float4*       dst = reinterpret_cast<float4*>(pos_vecs) + n * D4;
    float4 v[4];
    float ss = 0.f;
#pragma unroll
    for (int i = 0; i < 4; ++i) {
        v[i] = src[tid + 256 * i];
        ss += v[i].x * v[i].x + v[i].y * v[i].y + v[i].z * v[i].z + v[i].w * v[i].w;
    }
#pragma unroll
    for (int off = 32; off > 0; off >>= 1) ss += __shfl_xor(ss, off, 64);
    __shared__ float wsum[4];
    const int lane = tid & 63, wv = tid >> 6;
    if (lane == 0) wsum[wv] = ss;
    __syncthreads();
    const float tot = wsum[0] + wsum[1] + wsum[2] + wsum[3];
    const float inv = 1.0f / fmaxf(sqrtf(tot), EPS);
#pragma unroll
    for (int i = 0; i < 4; ++i) {
        float4 o;
        o.x = v[i].x * inv; o.y = v[i].y * inv; o.z = v[i].z * inv; o.w = v[i].w * inv;
        dst[tid + 256 * i] = o;
    }
}

// Fused kernel: logits -> softmax -> gate-weighted PV sum, 4 rows per block.
__global__ __launch_bounds__(256) void cope_kernel(
        const float* __restrict__ qg,
        const float* __restrict__ pos_vecs,
        float* __restrict__ outg) {
    const int tid = threadIdx.x;
    const long row0 = (long)blockIdx.x * RPB;
    const float4* Q  = reinterpret_cast<const float4*>(qg);
    const float4* PV = reinterpret_cast<const float4*>(pos_vecs);
    float4*       O  = reinterpret_cast<float4*>(outg);

    // ---- Phase 1: partial dots q[row] . pv[n] ----
    float acc[RPB][NPOS];
#pragma unroll
    for (int r = 0; r < RPB; ++r)
#pragma unroll
        for (int n = 0; n < NPOS; ++n) acc[r][n] = 0.f;

#pragma unroll
    for (int it = 0; it < 4; ++it) {
        const int p = tid + it * 256;
        float4 q4[RPB];
#pragma unroll
        for (int r = 0; r < RPB; ++r) q4[r] = Q[(row0 + r) * D4 + p];
#pragma unroll
        for (int n = 0; n < NPOS; ++n) {
            const float4 pv = PV[n * D4 + p];
#pragma unroll
            for (int r = 0; r < RPB; ++r) {
                acc[r][n] += q4[r].x * pv.x + q4[r].y * pv.y
                           + q4[r].z * pv.z + q4[r].w * pv.w;
            }
        }
    }

    // ---- Wave butterfly reduce all 64 accumulators ----
#pragma unroll
    for (int r = 0; r < RPB; ++r)
#pragma unroll
        for (int n = 0; n < NPOS; ++n) {
            float v = acc[r][n];
            v += __shfl_xor(v, 1, 64);
            v += __shfl_xor(v, 2, 64);
            v += __shfl_xor(v, 4, 64);
            v += __shfl_xor(v, 8, 64);
            v += __shfl_xor(v, 16, 64);
            v += __shfl_xor(v, 32, 64);
            acc[r][n] = v;
        }

    __shared__ float partial[4][RPB * NPOS];
    __shared__ float gates[RPB][NPOS];
    const int lane = tid & 63, wv = tid >> 6;
    if (lane == 0) {
#pragma unroll
        for (int r = 0; r < RPB; ++r)
#pragma unroll
            for (int n = 0; n < NPOS; ++n) partial[wv][r * NPOS + n] = acc[r][n];
    }
    __syncthreads();

    // ---- Cross-wave combine + softmax (wave 0 only; 16-lane groups) ----
    if (tid < RPB * NPOS) {   // == 64, i.e. wave 0 fully active
        float s = partial[0][tid] + partial[1][tid] + partial[2][tid] + partial[3][tid];
        s *= SCALE;
        float m = s;
        m = fmaxf(m, __shfl_xor(m, 1, 64));
        m = fmaxf(m, __shfl_xor(m, 2, 64));
        m = fmaxf(m, __shfl_xor(m, 4, 64));
        m = fmaxf(m, __shfl_xor(m, 8, 64));
        const float e = expf(s - m);
        float sum = e;
        sum += __shfl_xor(sum, 1, 64);
        sum += __shfl_xor(sum, 2, 64);
        sum += __shfl_xor(sum, 4, 64);
        sum += __shfl_xor(sum, 8, 64);
        gates[tid >> 4][tid & 15] = e / sum;
    }
    __syncthreads();

    // ---- Broadcast gates to registers (vector LDS reads) ----
    float g[RPB][NPOS];
#pragma unroll
    for (int r = 0; r < RPB; ++r) {
#pragma unroll
        for (int k = 0; k < 4; ++k) {
            const float4 gv = reinterpret_cast<const float4*>(&gates[r][0])[k];
            g[r][4 * k + 0] = gv.x; g[r][4 * k + 1] = gv.y;
            g[r][4 * k + 2] = gv.z; g[r][4 * k + 3] = gv.w;
        }
    }

    // ---- Phase 2: out[row] = sum_n g[row][n] * pv[n] ----
#pragma unroll
    for (int it = 0; it < 4; ++it) {
        const int p = tid + it * 256;
        float4 pv[NPOS];
#pragma unroll
        for (int n = 0; n < NPOS; ++n) pv[n] = PV[n * D4 + p];
#pragma unroll
        for (int r = 0; r < RPB; ++r) {
            float4 o; o.x = 0.f; o.y = 0.f; o.z = 0.f; o.w = 0.f;
#pragma unroll
            for (int n = 0; n < NPOS; ++n) {
                o.x += g[r][n] * pv[n].x;
                o.y += g[r][n] * pv[n].y;
                o.z += g[r][n] * pv[n].z;
                o.w += g[r][n] * pv[n].w;
            }
            O[(row0 + r) * D4 + p] = o;
        }
    }
}

extern "C" void kernel_launch(void* const* d_in, const int* in_sizes, int n_in,
                              void* d_out, int out_size, void* d_ws, size_t ws_size,
                              hipStream_t stream) {
    const float* q       = (const float*)d_in[0];
    // d_in[1] is `x` — unused by the reference; do not read it.
    const float* pos_emb = (const float*)d_in[2];
    float* out      = (float*)d_out;
    float* pos_vecs = (float*)d_ws;          // 16*4096*4 B = 256 KiB scratch

    hipLaunchKernelGGL(normalize_pos_kernel, dim3(NPOS), dim3(256), 0, stream,
                       pos_emb, pos_vecs);

    const int BT = in_sizes[0] / D;          // 4*4096 = 16384 rows
    hipLaunchKernelGGL(cope_kernel, dim3(BT / RPB), dim3(256), 0, stream,
                       q, pos_vecs, out);
}